// Round 2
// baseline (308.901 us; speedup 1.0000x reference)
//
#include <hip/hip_runtime.h>
#include <math.h>
#include <float.h>

#define BN 32
#define CH 3
#define HH 512
#define WW 512
#define NP 4
#define EPS 128
#define HALF 64
#define MARGIN 32

#define PATCH_ELEMS (BN * NP * CH * EPS * EPS)   // 6291456
#define TILES 256                                 // 16x16 tiles of 32x32

// ---------------------------------------------------------------------------
// Phase 1: per-tile argmax across all maps. One wave per 32x32 tile.
// grid = BN*TILES/4 blocks of 256 threads (4 waves).
// ---------------------------------------------------------------------------
__global__ __launch_bounds__(256)
void tile_max_kernel(const float* __restrict__ umaps,
                     float* __restrict__ tvg, int* __restrict__ tidxg)
{
    const int g    = blockIdx.x * 4 + (threadIdx.x >> 6);   // global wave id
    const int b    = g >> 8;
    const int tile = g & 255;
    const int ty   = tile >> 4, tx = tile & 15;
    const int lane = threadIdx.x & 63;

    const float4* __restrict__ um4 = (const float4*)(umaps + (size_t)b * HH * WW);

    float bv = -INFINITY;
    int   bi = 0x7fffffff;
    #pragma unroll
    for (int t4 = 0; t4 < 4; ++t4) {
        const int e4   = lane + (t4 << 6);       // 0..255 float4s in tile
        const int row  = e4 >> 3;
        const int col4 = (e4 & 7) << 2;
        const int y    = (ty << 5) + row;
        const int x    = (tx << 5) + col4;
        const float4 v = um4[(y << 7) + (x >> 2)];
        const int base = (y << 9) + x;
        float vals[4] = {v.x, v.y, v.z, v.w};
        #pragma unroll
        for (int j = 0; j < 4; ++j)
            if (vals[j] > bv) { bv = vals[j]; bi = base + j; }   // ascending idx per lane
    }
    #pragma unroll
    for (int off = 32; off > 0; off >>= 1) {
        float ov = __shfl_down(bv, off);
        int   oi = __shfl_down(bi, off);
        if (ov > bv || (ov == bv && oi < bi)) { bv = ov; bi = oi; }
    }
    if (lane == 0) { tvg[b * TILES + tile] = bv; tidxg[b * TILES + tile] = bi; }
}

// ---------------------------------------------------------------------------
// Phase 2: greedy selection over cached tile maxima, incremental rescans.
// One block (256 threads) per batch map.
// ---------------------------------------------------------------------------
__global__ __launch_bounds__(256)
void select2_kernel(const float* __restrict__ umaps,
                    const float* __restrict__ tvg, const int* __restrict__ tidxg,
                    float* __restrict__ coords_out, int* __restrict__ coords_ws)
{
    const int b    = blockIdx.x;
    const int tid  = threadIdx.x;
    const int lane = tid & 63;
    const int wave = tid >> 6;

    const float4* __restrict__ um4 = (const float4*)(umaps + (size_t)b * HH * WW);

    __shared__ float tv[TILES];
    __shared__ int   tidx[TILES];
    __shared__ int   boxes[NP][4];    // margin-expanded x1,x2,y1,y2
    __shared__ float rv[4];
    __shared__ int   ri[4];

    tv[tid]   = tvg[b * TILES + tid];
    tidx[tid] = tidxg[b * TILES + tid];
    __syncthreads();

    for (int k = 0; k < NP; ++k) {
        // ---- argmax over 256 tile entries ----
        float bv = tv[tid];
        int   bi = tidx[tid];
        #pragma unroll
        for (int off = 32; off > 0; off >>= 1) {
            float ov = __shfl_down(bv, off);
            int   oi = __shfl_down(bi, off);
            if (ov > bv || (ov == bv && oi < bi)) { bv = ov; bi = oi; }
        }
        if (lane == 0) { rv[wave] = bv; ri[wave] = bi; }
        __syncthreads();

        if (tid == 0) {
            bv = rv[0]; bi = ri[0];
            for (int w = 1; w < 4; ++w)
                if (rv[w] > bv || (rv[w] == bv && ri[w] < bi)) { bv = rv[w]; bi = ri[w]; }
            const int yc = bi >> 9;
            const int xc = bi & 511;
            int x1 = max(0, xc - HALF), x2 = min(WW, xc + HALF);
            int y1 = max(0, yc - HALF), y2 = min(HH, yc + HALF);
            if (x2 - x1 < EPS) { if (x1 == 0) x2 = EPS; else x1 = x2 - EPS; }
            if (y2 - y1 < EPS) { if (y1 == 0) y2 = EPS; else y1 = y2 - EPS; }
            boxes[k][0] = x1 - MARGIN; boxes[k][1] = x2 + MARGIN;
            boxes[k][2] = y1 - MARGIN; boxes[k][3] = y2 + MARGIN;

            const int o = (b * NP + k) * 4;
            coords_out[o + 0] = (float)x1;
            coords_out[o + 1] = (float)y1;
            coords_out[o + 2] = (float)x2;
            coords_out[o + 3] = (float)y2;
            coords_ws[(b * NP + k) * 2 + 0] = x1;
            coords_ws[(b * NP + k) * 2 + 1] = y1;
        }
        __syncthreads();

        if (k == NP - 1) break;

        // ---- rescan tiles touched by the NEW box against all boxes so far ----
        const int bx1 = max(boxes[k][0], 0), bx2 = min(boxes[k][1], WW);
        const int by1 = max(boxes[k][2], 0), by2 = min(boxes[k][3], HH);
        const int tx1 = bx1 >> 5, tx2 = (bx2 - 1) >> 5;
        const int ty1 = by1 >> 5, ty2 = (by2 - 1) >> 5;
        const int ntx = tx2 - tx1 + 1;
        const int nt  = ntx * (ty2 - ty1 + 1);

        for (int t = wave; t < nt; t += 4) {
            const int ty = ty1 + t / ntx;
            const int tx = tx1 + t % ntx;
            float nv = -INFINITY;
            int   ni = 0x7fffffff;
            #pragma unroll
            for (int t4 = 0; t4 < 4; ++t4) {
                const int e4   = lane + (t4 << 6);
                const int row  = e4 >> 3;
                const int col4 = (e4 & 7) << 2;
                const int y    = (ty << 5) + row;
                const int x    = (tx << 5) + col4;
                const float4 v = um4[(y << 7) + (x >> 2)];
                const int base = (y << 9) + x;
                float vals[4] = {v.x, v.y, v.z, v.w};
                #pragma unroll
                for (int j = 0; j < 4; ++j) {
                    const int xe = x + j;
                    bool masked = false;
                    for (int jb = 0; jb <= k; ++jb)
                        masked |= (y  >= boxes[jb][2]) & (y  < boxes[jb][3]) &
                                  (xe >= boxes[jb][0]) & (xe < boxes[jb][1]);
                    if (!masked && vals[j] > nv) { nv = vals[j]; ni = base + j; }
                }
            }
            #pragma unroll
            for (int off = 32; off > 0; off >>= 1) {
                float ov = __shfl_down(nv, off);
                int   oi = __shfl_down(ni, off);
                if (ov > nv || (ov == nv && oi < ni)) { nv = ov; ni = oi; }
            }
            if (lane == 0) { tv[(ty << 4) + tx] = nv; tidx[(ty << 4) + tx] = ni; }
        }
        __syncthreads();
    }
}

// ---------------------------------------------------------------------------
// Phase 3: patch gather. 4 px per thread, float4 stores.
// ---------------------------------------------------------------------------
__global__ __launch_bounds__(256)
void extract_kernel(const float* __restrict__ images,
                    const int* __restrict__ coords_ws,
                    float4* __restrict__ out4)
{
    const int i4   = blockIdx.x * 256 + threadIdx.x;   // < PATCH_ELEMS/4
    const int px0  = (i4 & 31) << 2;
    const int py   = (i4 >> 5) & 127;
    const int rest = i4 >> 12;           // b*NP*CH + n*CH + c
    const int c    = rest % CH;
    const int bn   = rest / CH;
    const int b    = bn >> 2;

    const int x1 = coords_ws[bn * 2 + 0];
    const int y1 = coords_ws[bn * 2 + 1];

    const float* __restrict__ src =
        images + (((size_t)b * CH + c) * HH + (y1 + py)) * WW + x1 + px0;
    out4[i4] = make_float4(src[0], src[1], src[2], src[3]);
}

extern "C" void kernel_launch(void* const* d_in, const int* in_sizes, int n_in,
                              void* d_out, int out_size, void* d_ws, size_t ws_size,
                              hipStream_t stream) {
    const float* images = (const float*)d_in[0];
    const float* umaps  = (const float*)d_in[1];
    float* out          = (float*)d_out;

    char* ws = (char*)d_ws;
    int*   coords_ws = (int*)ws;                              // 256 ints
    float* tvg       = (float*)(ws + 1024);                   // 8192 floats
    int*   tidxg     = (int*)(ws + 1024 + BN * TILES * 4);    // 8192 ints

    float* coords_out = out + PATCH_ELEMS;

    tile_max_kernel<<<BN * TILES / 4, 256, 0, stream>>>(umaps, tvg, tidxg);
    select2_kernel<<<BN, 256, 0, stream>>>(umaps, tvg, tidxg, coords_out, coords_ws);
    extract_kernel<<<PATCH_ELEMS / 4 / 256, 256, 0, stream>>>(images, coords_ws, (float4*)out);
}